// Round 1
// baseline (250.613 us; speedup 1.0000x reference)
//
#include <hip/hip_runtime.h>
#include <math.h>

// Problem constants (from reference setup_inputs)
#define B_    8
#define F_    64        // features
#define HW_   65536     // 256*256 pixels
#define NSEG  33        // N_OBJECTS + 1
#define NOBJ  32
#define CHUNK 1024      // pixels per block in segmax kernel
#define CPB   (HW_ / CHUNK)   // 64 chunks per batch
#define ENC_NEG_INF 0x007FFFFFu   // monotonic encoding of -inf

// Monotonic order-preserving float->uint encoding: unsigned max == float max.
__device__ __forceinline__ unsigned enc_f(float x) {
    unsigned u = __float_as_uint(x);
    return u ^ ((unsigned)((int)u >> 31) | 0x80000000u);
}
__device__ __forceinline__ float dec_f(unsigned e) {
    unsigned x = (e & 0x80000000u) ? (e ^ 0x80000000u) : ~e;
    return __uint_as_float(x);
}

// d_ws is poisoned 0xAA before every timed launch -> must re-init every call.
__global__ void init_ws(unsigned* __restrict__ gws) {
    int i = blockIdx.x * blockDim.x + threadIdx.x;
    if (i < B_ * NSEG * F_) gws[i] = ENC_NEG_INF;
}

// One block = one (batch, 1024-pixel chunk). Streams all 64 features for that
// chunk with float4 loads; per-block LDS accumulator [f][seg] via ds atomics;
// flush with global atomicMax on encoded uints.
__global__ __launch_bounds__(256) void segmax_kernel(
        const float* __restrict__ enc, const int* __restrict__ masks,
        unsigned* __restrict__ gws) {
    __shared__ unsigned acc[F_ * NSEG];   // 8448 B
    const int tid   = threadIdx.x;
    const int b     = blockIdx.x / CPB;
    const int chunk = blockIdx.x % CPB;

    for (int i = tid; i < F_ * NSEG; i += 256) acc[i] = ENC_NEG_INF;

    // Each thread owns 4 consecutive pixels (same pixels for every feature).
    const int4 ids = ((const int4*)(masks + b * HW_ + chunk * CHUNK))[tid];
    __syncthreads();

    const float4* p = (const float4*)(enc + (size_t)b * F_ * HW_ + chunk * CHUNK) + tid;
    #pragma unroll 4
    for (int f = 0; f < F_; ++f) {
        float4 v = p[(size_t)f * (HW_ / 4)];
        unsigned* a = acc + f * NSEG;   // [f][seg]: lane banks spread by id
        atomicMax(a + ids.x, enc_f(v.x));
        atomicMax(a + ids.y, enc_f(v.y));
        atomicMax(a + ids.z, enc_f(v.z));
        atomicMax(a + ids.w, enc_f(v.w));
    }
    __syncthreads();

    unsigned* gb = gws + b * (NSEG * F_);   // global layout [b][seg][f]
    for (int i = tid; i < F_ * NSEG; i += 256) {
        unsigned val = acc[i];
        if (val != ENC_NEG_INF) {
            int f = i / NSEG, s = i % NSEG;
            atomicMax(gb + s * F_ + f, val);
        }
    }
}

// One block per batch. Decode vectors, write them out, then the pairwise MLP:
// h[b,i,j,k] = (v_i @ W1[0:64]) + (v_j @ W1[64:128]) + b1  -> sigmoid(h @ W2 + b2)
// connections[b,c,j,i] = out[b,i,j,c]
__global__ __launch_bounds__(256) void mlp_kernel(
        const unsigned* __restrict__ gws,
        const float* __restrict__ W1, const float* __restrict__ b1,
        const float* __restrict__ W2, const float* __restrict__ b2,
        float* __restrict__ out_vec, float* __restrict__ out_conn) {
    const int b = blockIdx.x;
    const int tid = threadIdx.x;
    __shared__ float v[NOBJ * F_];     // [i][f]
    __shared__ float Am[NOBJ * 33];    // A[i][k] + b1[k], stride 33 (bank pad)
    __shared__ float Bm[NOBJ * 33];    // B[j][k]

    // Decode segments 1..32 (segment 0 dropped by reference).
    for (int i = tid; i < NOBJ * F_; i += 256) {
        int s = (i >> 6) + 1, f = i & 63;
        float val = dec_f(gws[b * NSEG * F_ + s * F_ + f]);
        v[i] = val;
        out_vec[b * NOBJ * F_ + i] = val;
    }
    __syncthreads();

    // A[i][k] and B[j][k]: 2048 dots of length 64.
    for (int e = tid; e < 2 * NOBJ * 32; e += 256) {
        int half = e >> 10;             // 0 -> A (W1 rows 0..63), 1 -> B (rows 64..127)
        int idx  = e & 1023;
        int i = idx >> 5, k = idx & 31;
        const float* vv = v + i * F_;
        const float* w  = W1 + (half ? F_ * 32 : 0) + k;   // W1[d][k], row stride 32
        float s = 0.f;
        #pragma unroll
        for (int f = 0; f < F_; ++f) s = fmaf(vv[f], w[f * 32], s);
        if (half) Bm[i * 33 + k] = s;
        else      Am[i * 33 + k] = s + b1[k];
    }
    __syncthreads();

    // 1024 (i,j) pairs -> 4 sigmoid outputs each.
    for (int e = tid; e < NOBJ * NOBJ; e += 256) {
        int i = e >> 5, j = e & 31;
        float o0 = b2[0], o1 = b2[1], o2 = b2[2], o3 = b2[3];
        #pragma unroll
        for (int k = 0; k < 32; ++k) {
            float h = Am[i * 33 + k] + Bm[j * 33 + k];
            o0 = fmaf(h, W2[k * 4 + 0], o0);
            o1 = fmaf(h, W2[k * 4 + 1], o1);
            o2 = fmaf(h, W2[k * 4 + 2], o2);
            o3 = fmaf(h, W2[k * 4 + 3], o3);
        }
        float* oc = out_conn + (size_t)b * 4 * NOBJ * NOBJ + j * NOBJ + i;
        oc[0 * NOBJ * NOBJ] = 1.f / (1.f + expf(-o0));
        oc[1 * NOBJ * NOBJ] = 1.f / (1.f + expf(-o1));
        oc[2 * NOBJ * NOBJ] = 1.f / (1.f + expf(-o2));
        oc[3 * NOBJ * NOBJ] = 1.f / (1.f + expf(-o3));
    }
}

extern "C" void kernel_launch(void* const* d_in, const int* in_sizes, int n_in,
                              void* d_out, int out_size, void* d_ws, size_t ws_size,
                              hipStream_t stream) {
    const float* enc   = (const float*)d_in[0];
    const int*   masks = (const int*)  d_in[1];
    const float* W1    = (const float*)d_in[2];
    const float* b1    = (const float*)d_in[3];
    const float* W2    = (const float*)d_in[4];
    const float* b2    = (const float*)d_in[5];

    float* out_vec  = (float*)d_out;                 // 8*32*64 = 16384 floats
    float* out_conn = out_vec + B_ * NOBJ * F_;      // 8*4*32*32 = 32768 floats
    unsigned* gws   = (unsigned*)d_ws;               // 8*33*64 uints = 67.6 KB

    const int n = B_ * NSEG * F_;
    init_ws<<<(n + 255) / 256, 256, 0, stream>>>(gws);
    segmax_kernel<<<B_ * CPB, 256, 0, stream>>>(enc, masks, gws);
    mlp_kernel<<<B_, 256, 0, stream>>>(gws, W1, b1, W2, b2, out_vec, out_conn);
}